// Round 5
// baseline (325.076 us; speedup 1.0000x reference)
//
#include <hip/hip_runtime.h>

// Problem constants (B=8, C=512, H=W=64, K=19 classes)
#define NCLS   19
#define NB     8
#define NC     512
#define NHW    4096      // 64*64
#define EPSM   1e-6f     // mean denominator eps
#define EPSC   1e-8f     // cosine eps
#define GCH    2         // channels per block in k_sums

// Workspace layout (bytes)
#define OFF_LABELS   0u          // int32 [NB*NHW]
#define OFF_COUNTS   131072u     // float [NB*NCLS] ([b][k])
#define OFF_SUMS_S   132096u     // float [NB][NCLS][NC]  (means S after k_means, in place)
#define OFF_SUMS_T   443392u     // float [NB][NCLS][NC]  (means T after k_means, in place)
#define OFF_NORM_S   754688u     // float [NB*NCLS]
#define OFF_NORM_T   755712u     // float [NB*NCLS]
#define OFF_PART     756736u     // float [4 arrays][8 chunks][NB*NHW] (k_dots partials)
// total = 756736 + 4*8*32768*4 = 4,951,040 B

// ---------------------------------------------------------------------------
// Wave-64 sum via DPP (VALU pipe only, no LDS). Result valid in lane 63.
template<int CTRL>
__device__ __forceinline__ float dpp_add(float x) {
    int y = __builtin_amdgcn_update_dpp(0, __float_as_int(x), CTRL, 0xf, 0xf, false);
    return x + __int_as_float(y);
}
__device__ __forceinline__ float wave64_sum(float x) {
    x = dpp_add<0x111>(x);   // row_shr:1
    x = dpp_add<0x112>(x);   // row_shr:2
    x = dpp_add<0x114>(x);   // row_shr:4
    x = dpp_add<0x118>(x);   // row_shr:8  -> lane15 of each row16 has row sum
    x = dpp_add<0x142>(x);   // row_bcast:15 -> lane31/63 have half sums
    x = dpp_add<0x143>(x);   // row_bcast:31 -> lane63 has total
    return x;
}

// ---------------------------------------------------------------------------
// Kernel 1: nearest-resize labels (512x512 -> 64x64) + per-batch class counts
__global__ __launch_bounds__(256) void k_labels(const int* __restrict__ target,
                                                int* __restrict__ labels,
                                                float* __restrict__ counts) {
    __shared__ int hist[NCLS];
    const int b = blockIdx.x;
    const int t = threadIdx.x;
    if (t < NCLS) hist[t] = 0;
    __syncthreads();
    const int* tb = target + (size_t)b * 512 * 512;
    #pragma unroll
    for (int i = 0; i < 16; ++i) {
        int n = t + i * 256;
        int y = n >> 6, x = n & 63;
        int l = tb[(y * 8) * 512 + x * 8];   // in_idx = floor(out_idx*512/64)
        labels[b * NHW + n] = l;
        if (l >= 0 && l < NCLS) atomicAdd(&hist[l], 1);
    }
    __syncthreads();
    if (t < NCLS) counts[b * NCLS + t] = (float)hist[t];
}

// ---------------------------------------------------------------------------
// Kernel 2: per-class channel sums via LDS-ATOMIC SEGMENT SCATTER.
//
// ALGORITHM HISTORY (load-bearing):
//   Rounds 0-4 used mask-and-accumulate: 19 compare/select/FMA per element
//   = O(NCLS)/element -> ~30 us VALU-issue floor (round 4 measured: occ 55%,
//   VALUBusy 54%, dur 57 us — occupancy tripled vs round 0, time ~flat,
//   falsifying the latency theory; the algorithm itself was the bottleneck).
//   This version: one ds_add_f32 per element = O(1)/element. LDS-pipe cost
//   ~2048 wave-atomics/CU x ~16-24cy (same-address serialization ~= max
//   label multiplicity ~7 of 64 random lanes) ~= 15-20 us, VALU ~idle.
//
// Block owns (b, 2 channels), all 4096 pixels -> writes sums[b][k][c0..c0+1]
// exclusively (no partials, no global atomics). acc row stride 5 floats:
// gcd(5,32)=1 -> the 19 class rows hit 19 distinct banks per atomic instr;
// only same-label lanes serialize. Labels here are uniform random 0..18.
// Grid: 8*256=2048 blocks x 256 thr = 8 blocks/CU = 32 waves/CU supply.
// FALLBACK (pre-committed): if this lands >=45 us with huge
// SQ_LDS_BANK_CONFLICT, revert to round-4 masks + LDS-staged loads.
__global__ __launch_bounds__(256) void k_sums(const float* __restrict__ fS,
                                              const float* __restrict__ fT,
                                              const int* __restrict__ labels,
                                              float* __restrict__ sumsS,
                                              float* __restrict__ sumsT) {
    __shared__ float acc[NCLS][5];           // slots 0..3 = (ci*2+tensor); col 4 = pad
    const int t   = threadIdx.x;
    const int blk = blockIdx.x;              // 0..2047
    const int b   = blk >> 8;                // NC/GCH = 256 blocks per batch
    const int cg  = blk & 255;
    const int c0  = cg * GCH;

    for (int i = t; i < NCLS * 5; i += 256) ((float*)acc)[i] = 0.f;
    __syncthreads();

    // Thread's 16 pixels: float4 index t + 256*j (lane-consecutive, coalesced).
    const int4* lab4 = (const int4*)(labels + b * NHW);
    int4 lab[4];
    #pragma unroll
    for (int j = 0; j < 4; ++j) lab[j] = lab4[t + 256 * j];

    #pragma unroll
    for (int ci = 0; ci < GCH; ++ci) {
        const size_t base = ((size_t)(b * NC) + c0 + ci) * NHW;
        const float4* pS = (const float4*)(fS + base);
        const float4* pT = (const float4*)(fT + base);
        const int sS = ci * 2, sT = ci * 2 + 1;
        #pragma unroll
        for (int j = 0; j < 4; ++j) {
            const float4 vS = pS[t + 256 * j];
            const float4 vT = pT[t + 256 * j];
            const int4 l = lab[j];
            if ((unsigned)l.x < NCLS) { atomicAdd(&acc[l.x][sS], vS.x); atomicAdd(&acc[l.x][sT], vT.x); }
            if ((unsigned)l.y < NCLS) { atomicAdd(&acc[l.y][sS], vS.y); atomicAdd(&acc[l.y][sT], vT.y); }
            if ((unsigned)l.z < NCLS) { atomicAdd(&acc[l.z][sS], vS.z); atomicAdd(&acc[l.z][sT], vT.z); }
            if ((unsigned)l.w < NCLS) { atomicAdd(&acc[l.w][sS], vS.w); atomicAdd(&acc[l.w][sT], vT.w); }
        }
    }
    __syncthreads();

    // Write 19 classes x GCH channels x 2 tensors = 76 values, k-major layout.
    for (int i = t; i < NCLS * GCH * 2; i += 256) {
        const int k  = i / (GCH * 2);
        const int s  = i % (GCH * 2);
        const int ci = s >> 1, ten = s & 1;
        float* dst = (ten ? sumsT : sumsS) + ((size_t)(b * NCLS + k)) * NC + c0 + ci;
        *dst = acc[k][s];
    }
}

// ---------------------------------------------------------------------------
// Kernel 3: means = sums/(count+eps) in place + per-(b,k) center norms.
// One wave per (b,k); sums layout [b][k][c] -> coalesced.
__global__ __launch_bounds__(64) void k_means(float* __restrict__ sumsS,
                                              float* __restrict__ sumsT,
                                              const float* __restrict__ counts,
                                              float* __restrict__ normS,
                                              float* __restrict__ normT) {
    const int bk = blockIdx.x;
    const int t = threadIdx.x;
    const float inv = 1.f / (counts[bk] + EPSM);
    float* rS = sumsS + (size_t)bk * NC;
    float* rT = sumsT + (size_t)bk * NC;
    float aS = 0.f, aT = 0.f;
    #pragma unroll
    for (int i = 0; i < NC / 64; ++i) {
        float mS = rS[t + i * 64] * inv; rS[t + i * 64] = mS; aS += mS * mS;
        float mT = rT[t + i * 64] * inv; rT[t + i * 64] = mT; aT += mT * mT;
    }
    aS = wave64_sum(aS);
    aT = wave64_sum(aT);
    if (t == 63) { normS[bk] = sqrtf(aS); normT[bk] = sqrtf(aT); }
}

// ---------------------------------------------------------------------------
// Kernel 4: per-pixel dot(f, mean[lab]) and ||f||^2, atomic-free.
// Grid: 8 b x 16 pixel-tiles x 8 c-chunks = 1024 blocks.
// Means tile in LDS as [class][65] -> gather bank = (l+ci)%32, conflict-free.
#define CCH 64
__global__ __launch_bounds__(256) void k_dots(const float* __restrict__ fS,
                                              const float* __restrict__ fT,
                                              const float* __restrict__ meansS,
                                              const float* __restrict__ meansT,
                                              const int* __restrict__ labels,
                                              float* __restrict__ part) {
    __shared__ float mS[NCLS * 65];
    __shared__ float mT[NCLS * 65];
    const int blk = blockIdx.x;
    const int chunk = blk & 7;
    const int tile  = (blk >> 3) & 15;
    const int b     = blk >> 7;
    const int t = threadIdx.x;
    const int c0 = chunk * CCH;
    const int n = tile * 256 + t;

    for (int i = t; i < NCLS * CCH; i += 256) {
        const int k = i >> 6, j = i & 63;
        mS[k * 65 + j] = meansS[((size_t)(b * NCLS + k)) * NC + c0 + j];
        mT[k * 65 + j] = meansT[((size_t)(b * NCLS + k)) * NC + c0 + j];
    }
    __syncthreads();

    const int l = labels[b * NHW + n];
    const int lc = (l >= 0 && l < NCLS) ? l : 0;
    const float* pS = fS + ((size_t)(b * NC + c0)) * NHW + n;
    const float* pT = fT + ((size_t)(b * NC + c0)) * NHW + n;
    float dS = 0.f, nS = 0.f, dT = 0.f, nT = 0.f;
    #pragma unroll 8
    for (int ci = 0; ci < CCH; ++ci) {
        const float vS = pS[(size_t)ci * NHW];
        const float vT = pT[(size_t)ci * NHW];
        const float ms = mS[lc * 65 + ci];
        const float mt = mT[lc * 65 + ci];
        dS += vS * ms; nS += vS * vS;
        dT += vT * mt; nT += vT * vT;
    }
    const int p = b * NHW + n;
    part[((size_t)(0 * 8 + chunk)) * (NB * NHW) + p] = dS;
    part[((size_t)(1 * 8 + chunk)) * (NB * NHW) + p] = nS;
    part[((size_t)(2 * 8 + chunk)) * (NB * NHW) + p] = dT;
    part[((size_t)(3 * 8 + chunk)) * (NB * NHW) + p] = nT;
}

// ---------------------------------------------------------------------------
// Kernel 5: combine partials, cosines, MSE reduce.
__global__ __launch_bounds__(256) void k_final(const float* __restrict__ part,
                                               const int* __restrict__ labels,
                                               const float* __restrict__ normS,
                                               const float* __restrict__ normT,
                                               float* __restrict__ out) {
    __shared__ float red[4];
    const int p = blockIdx.x * 256 + threadIdx.x;
    const int b = p >> 12;
    float dS = 0.f, nS = 0.f, dT = 0.f, nT = 0.f;
    #pragma unroll
    for (int ch = 0; ch < 8; ++ch) {
        dS += part[((size_t)(0 * 8 + ch)) * (NB * NHW) + p];
        nS += part[((size_t)(1 * 8 + ch)) * (NB * NHW) + p];
        dT += part[((size_t)(2 * 8 + ch)) * (NB * NHW) + p];
        nT += part[((size_t)(3 * 8 + ch)) * (NB * NHW) + p];
    }
    const int l = labels[p];
    float val = 0.f;
    if (l >= 0 && l < NCLS) {
        float cS = dS / (fmaxf(sqrtf(nS), EPSC) * fmaxf(normS[b * NCLS + l], EPSC));
        float cT = dT / (fmaxf(sqrtf(nT), EPSC) * fmaxf(normT[b * NCLS + l], EPSC));
        float d = cS - cT;
        val = d * d;
    }
    val = wave64_sum(val);
    if ((threadIdx.x & 63) == 63) red[threadIdx.x >> 6] = val;
    __syncthreads();
    if (threadIdx.x == 0)
        atomicAdd(out, (red[0] + red[1] + red[2] + red[3]) * (1.f / (NB * NHW)));
}

// ---------------------------------------------------------------------------
extern "C" void kernel_launch(void* const* d_in, const int* in_sizes, int n_in,
                              void* d_out, int out_size, void* d_ws, size_t ws_size,
                              hipStream_t stream) {
    (void)in_sizes; (void)n_in; (void)out_size; (void)ws_size;
    const float* fS     = (const float*)d_in[0];
    const float* fT     = (const float*)d_in[1];
    const int*   target = (const int*)d_in[2];

    char* ws = (char*)d_ws;
    int*   labels = (int*)  (ws + OFF_LABELS);
    float* counts = (float*)(ws + OFF_COUNTS);
    float* sumsS  = (float*)(ws + OFF_SUMS_S);   // means after k_means (in place)
    float* sumsT  = (float*)(ws + OFF_SUMS_T);
    float* normS  = (float*)(ws + OFF_NORM_S);
    float* normT  = (float*)(ws + OFF_NORM_T);
    float* part   = (float*)(ws + OFF_PART);

    hipMemsetAsync(d_out, 0, sizeof(float), stream);

    k_labels<<<NB, 256, 0, stream>>>(target, labels, counts);
    k_sums  <<<NB * (NC / GCH), 256, 0, stream>>>(fS, fT, labels, sumsS, sumsT);
    k_means <<<NB * NCLS, 64, 0, stream>>>(sumsS, sumsT, counts, normS, normT);
    k_dots  <<<NB * 16 * 8, 256, 0, stream>>>(fS, fT, sumsS, sumsT, labels, part);
    k_final <<<NB * NHW / 256, 256, 0, stream>>>(part, labels, normS, normT,
                                                 (float*)d_out);
}

// Round 6
// 202.960 us; speedup vs baseline: 1.6017x; 1.6017x over previous
//
#include <hip/hip_runtime.h>

// Problem constants (B=8, C=512, H=W=64, K=19 classes)
#define NCLS   19
#define NB     8
#define NC     512
#define NHW    4096      // 64*64
#define EPSM   1e-6f     // mean denominator eps
#define EPSC   1e-8f     // cosine eps
#define NSEG   2         // pixel segments per channel-pair in k_sums
#define KPW    5         // classes per wave in k_sums (4 waves: 5/5/5/4+pad)
#define LBLK   8         // k_labels blocks per batch

// Workspace layout (bytes)
#define OFF_LABELS   0u          // int32 [NB*NHW]
#define OFF_COUNTS   131072u     // float [NB*NCLS] ([b][k])
#define OFF_SUMS_S   132096u     // float [NB][NCLS][NC]  (means S after k_means)
#define OFF_SUMS_T   443392u     // float [NB][NCLS][NC]  (means T after k_means)
#define OFF_NORM_S   754688u     // float [NB*NCLS]
#define OFF_NORM_T   755712u     // float [NB*NCLS]
#define OFF_PART     756736u     // float [4 arrays][8 chunks][NB*NHW] (k_dots partials)
// k_sums segment-partials temporally reuse OFF_PART (consumed by k_means
// before k_dots writes its partials — same stream, serialized):
#define PSEG_BYTES   622592u     // NSEG*NB*NCLS*NC*4 bytes per tensor
// total = 756736 + 4*8*32768*4 = 4,951,040 B

// ---------------------------------------------------------------------------
// Wave-64 sum via DPP (VALU pipe only, no LDS). Result valid in lane 63.
template<int CTRL>
__device__ __forceinline__ float dpp_add(float x) {
    int y = __builtin_amdgcn_update_dpp(0, __float_as_int(x), CTRL, 0xf, 0xf, false);
    return x + __int_as_float(y);
}
__device__ __forceinline__ float wave64_sum(float x) {
    x = dpp_add<0x111>(x);   // row_shr:1
    x = dpp_add<0x112>(x);   // row_shr:2
    x = dpp_add<0x114>(x);   // row_shr:4
    x = dpp_add<0x118>(x);   // row_shr:8  -> lane15 of each row16 has row sum
    x = dpp_add<0x142>(x);   // row_bcast:15 -> lane31/63 have half sums
    x = dpp_add<0x143>(x);   // row_bcast:31 -> lane63 has total
    return x;
}

// ---------------------------------------------------------------------------
// Kernel 1: nearest-resize labels + per-batch class counts.
// Parallelized 8 -> 64 blocks (was 8 blocks = 3% of chip). Per-block LDS
// hist, then one float atomicAdd per (block,class) into zeroed counts —
// integer-valued f32 adds are exact and order-independent.
__global__ __launch_bounds__(256) void k_labels(const int* __restrict__ target,
                                                int* __restrict__ labels,
                                                float* __restrict__ counts) {
    __shared__ int hist[NCLS];
    const int blk = blockIdx.x;          // 0..63
    const int b    = blk >> 3;
    const int part = blk & (LBLK - 1);   // 512-pixel slice
    const int t = threadIdx.x;
    if (t < NCLS) hist[t] = 0;
    __syncthreads();
    const int* tb = target + (size_t)b * 512 * 512;
    #pragma unroll
    for (int i = 0; i < 2; ++i) {
        int n = part * 512 + t + i * 256;
        int y = n >> 6, x = n & 63;
        int l = tb[(y * 8) * 512 + x * 8];   // in_idx = floor(out_idx*512/64)
        labels[b * NHW + n] = l;
        if (l >= 0 && l < NCLS) atomicAdd(&hist[l], 1);
    }
    __syncthreads();
    if (t < NCLS && hist[t] > 0)
        atomicAdd(&counts[b * NCLS + t], (float)hist[t]);
}

// ---------------------------------------------------------------------------
// Kernel 2: per-class channel sums. Class-split-across-waves (round-4 body).
//
// OCCUPANCY MODEL (fitted over rounds 0-5, all configs):
//   residency = min( floor(256/VGPR), launch_bounds 2nd arg if present )
//     r0/r2 (256,2) VGPR96 -> 2 (cap)     r3 (256) VGPR96 -> 2 (VGPR floor)
//     r1 (256,4) VGPR64 -> 4 (cap)        r4 (256,4) VGPR36 -> 4 (CAP, not 7!)
// This version: round-4 kernel with the waves-arg REMOVED. VGPR ~36 ->
// 7 waves/SIMD resident (grid supplies 16). Round 4 measured occ 55% /
// VALUBusy 54% / 57.4 us; the residual stall is latency 3 extra waves cover.
// ALGORITHM: wave w of each block accumulates classes [5w,5w+5) (wave 3 pads
// k=19, write-guarded); block owns (b, channel-pair, pixel-half). Masks per
// class computed by exactly one wave -> total VALU unchanged vs round 0.
// (Round 5's LDS-atomic variant: 174 us — colliding ds_add serializes
// per-lane on the CU's single LDS pipe, ~204 cy/wave-atomic. Do not revisit.)
__global__ __launch_bounds__(256) void k_sums(const float* __restrict__ fS,
                                              const float* __restrict__ fT,
                                              const int* __restrict__ labels,
                                              float* __restrict__ partS,
                                              float* __restrict__ partT) {
    const int t = threadIdx.x;
    const int lane = t & 63;
    const int w = t >> 6;                          // wave 0..3 -> class group
    const int blk = blockIdx.x;                    // 0..4095
    const int b   = blk >> 9;                      // 512 blocks per batch
    const int r   = blk & 511;
    const int c0  = (r >> 1) << 1;                 // channels c0, c0+1
    const int seg = r & 1;                         // pixel half
    const int k0  = w * KPW;                       // first class of this wave

    const size_t base = ((size_t)(b * NC) + c0) * NHW;
    const float4* pS0 = (const float4*)(fS + base);
    const float4* pS1 = (const float4*)(fS + base + NHW);
    const float4* pT0 = (const float4*)(fT + base);
    const float4* pT1 = (const float4*)(fT + base + NHW);
    const int4* lab4 = (const int4*)(labels + b * NHW);

    float aS0[KPW], aS1[KPW], aT0[KPW], aT1[KPW];
    #pragma unroll
    for (int j = 0; j < KPW; ++j) { aS0[j] = aS1[j] = aT0[j] = aT1[j] = 0.f; }

    for (int i = 0; i < 8; ++i) {
        const int idx = (seg << 9) + lane + (i << 6);   // float4 index (4 pixels)
        const float4 vS0 = pS0[idx];
        const float4 vS1 = pS1[idx];
        const float4 vT0 = pT0[idx];
        const float4 vT1 = pT1[idx];
        const int4 l = lab4[idx];
        #pragma unroll
        for (int j = 0; j < KPW; ++j) {            // static acc index (no scratch)
            const int k = k0 + j;                  // runtime-uniform class id
            const float m0 = (l.x == k) ? 1.f : 0.f;
            const float m1 = (l.y == k) ? 1.f : 0.f;
            const float m2 = (l.z == k) ? 1.f : 0.f;
            const float m3 = (l.w == k) ? 1.f : 0.f;
            aS0[j] += m0 * vS0.x + m1 * vS0.y + m2 * vS0.z + m3 * vS0.w;
            aS1[j] += m0 * vS1.x + m1 * vS1.y + m2 * vS1.z + m3 * vS1.w;
            aT0[j] += m0 * vT0.x + m1 * vT0.y + m2 * vT0.z + m3 * vT0.w;
            aT1[j] += m0 * vT1.x + m1 * vT1.y + m2 * vT1.z + m3 * vT1.w;
        }
    }
    // Cross-lane reduce each accumulator (DPP, lane 63 holds totals)
    #pragma unroll
    for (int j = 0; j < KPW; ++j) {
        aS0[j] = wave64_sum(aS0[j]);
        aS1[j] = wave64_sum(aS1[j]);
        aT0[j] = wave64_sum(aT0[j]);
        aT1[j] = wave64_sum(aT1[j]);
    }
    if (lane == 63) {
        const size_t segoff = (size_t)seg * (NB * NCLS);
        #pragma unroll
        for (int j = 0; j < KPW; ++j) {
            const int k = k0 + j;
            if (k < NCLS) {                        // wave 3's pad class 19: skip
                float2* dS = (float2*)(partS + (segoff + (size_t)(b * NCLS + k)) * NC + c0);
                float2* dT = (float2*)(partT + (segoff + (size_t)(b * NCLS + k)) * NC + c0);
                *dS = make_float2(aS0[j], aS1[j]);
                *dT = make_float2(aT0[j], aT1[j]);
            }
        }
    }
}

// ---------------------------------------------------------------------------
// Kernel 3: combine segment partials, means = sum/(count+eps), per-(b,k)
// center norms. One wave per (b,k); all layouts [b][k][c] -> coalesced.
// Deterministic summation order (seg0 + seg1).
__global__ __launch_bounds__(64) void k_means(const float* __restrict__ partS,
                                              const float* __restrict__ partT,
                                              float* __restrict__ meansS,
                                              float* __restrict__ meansT,
                                              const float* __restrict__ counts,
                                              float* __restrict__ normS,
                                              float* __restrict__ normT) {
    const int bk = blockIdx.x;
    const int t = threadIdx.x;
    const float inv = 1.f / (counts[bk] + EPSM);
    const size_t s0 = (size_t)bk * NC;
    const size_t s1 = (size_t)(NB * NCLS + bk) * NC;
    float aS = 0.f, aT = 0.f;
    #pragma unroll
    for (int i = 0; i < NC / 64; ++i) {
        const int c = t + i * 64;
        float mS = (partS[s0 + c] + partS[s1 + c]) * inv;
        float mT = (partT[s0 + c] + partT[s1 + c]) * inv;
        meansS[s0 + c] = mS; aS += mS * mS;
        meansT[s0 + c] = mT; aT += mT * mT;
    }
    aS = wave64_sum(aS);
    aT = wave64_sum(aT);
    if (t == 63) { normS[bk] = sqrtf(aS); normT[bk] = sqrtf(aT); }
}

// ---------------------------------------------------------------------------
// Kernel 4: per-pixel dot(f, mean[lab]) and ||f||^2, atomic-free.
// Grid: 8 b x 16 pixel-tiles x 8 c-chunks = 1024 blocks.
// Means tile in LDS as [class][65] -> gather bank = (l+ci)%32, conflict-free.
#define CCH 64
__global__ __launch_bounds__(256) void k_dots(const float* __restrict__ fS,
                                              const float* __restrict__ fT,
                                              const float* __restrict__ meansS,
                                              const float* __restrict__ meansT,
                                              const int* __restrict__ labels,
                                              float* __restrict__ part) {
    __shared__ float mS[NCLS * 65];
    __shared__ float mT[NCLS * 65];
    const int blk = blockIdx.x;
    const int chunk = blk & 7;
    const int tile  = (blk >> 3) & 15;
    const int b     = blk >> 7;
    const int t = threadIdx.x;
    const int c0 = chunk * CCH;
    const int n = tile * 256 + t;

    for (int i = t; i < NCLS * CCH; i += 256) {
        const int k = i >> 6, j = i & 63;
        mS[k * 65 + j] = meansS[((size_t)(b * NCLS + k)) * NC + c0 + j];
        mT[k * 65 + j] = meansT[((size_t)(b * NCLS + k)) * NC + c0 + j];
    }
    __syncthreads();

    const int l = labels[b * NHW + n];
    const int lc = (l >= 0 && l < NCLS) ? l : 0;
    const float* pS = fS + ((size_t)(b * NC + c0)) * NHW + n;
    const float* pT = fT + ((size_t)(b * NC + c0)) * NHW + n;
    float dS = 0.f, nS = 0.f, dT = 0.f, nT = 0.f;
    #pragma unroll 8
    for (int ci = 0; ci < CCH; ++ci) {
        const float vS = pS[(size_t)ci * NHW];
        const float vT = pT[(size_t)ci * NHW];
        const float ms = mS[lc * 65 + ci];
        const float mt = mT[lc * 65 + ci];
        dS += vS * ms; nS += vS * vS;
        dT += vT * mt; nT += vT * vT;
    }
    const int p = b * NHW + n;
    part[((size_t)(0 * 8 + chunk)) * (NB * NHW) + p] = dS;
    part[((size_t)(1 * 8 + chunk)) * (NB * NHW) + p] = nS;
    part[((size_t)(2 * 8 + chunk)) * (NB * NHW) + p] = dT;
    part[((size_t)(3 * 8 + chunk)) * (NB * NHW) + p] = nT;
}

// ---------------------------------------------------------------------------
// Kernel 5: combine partials, cosines, MSE reduce.
__global__ __launch_bounds__(256) void k_final(const float* __restrict__ part,
                                               const int* __restrict__ labels,
                                               const float* __restrict__ normS,
                                               const float* __restrict__ normT,
                                               float* __restrict__ out) {
    __shared__ float red[4];
    const int p = blockIdx.x * 256 + threadIdx.x;
    const int b = p >> 12;
    float dS = 0.f, nS = 0.f, dT = 0.f, nT = 0.f;
    #pragma unroll
    for (int ch = 0; ch < 8; ++ch) {
        dS += part[((size_t)(0 * 8 + ch)) * (NB * NHW) + p];
        nS += part[((size_t)(1 * 8 + ch)) * (NB * NHW) + p];
        dT += part[((size_t)(2 * 8 + ch)) * (NB * NHW) + p];
        nT += part[((size_t)(3 * 8 + ch)) * (NB * NHW) + p];
    }
    const int l = labels[p];
    float val = 0.f;
    if (l >= 0 && l < NCLS) {
        float cS = dS / (fmaxf(sqrtf(nS), EPSC) * fmaxf(normS[b * NCLS + l], EPSC));
        float cT = dT / (fmaxf(sqrtf(nT), EPSC) * fmaxf(normT[b * NCLS + l], EPSC));
        float d = cS - cT;
        val = d * d;
    }
    val = wave64_sum(val);
    if ((threadIdx.x & 63) == 63) red[threadIdx.x >> 6] = val;
    __syncthreads();
    if (threadIdx.x == 0)
        atomicAdd(out, (red[0] + red[1] + red[2] + red[3]) * (1.f / (NB * NHW)));
}

// ---------------------------------------------------------------------------
extern "C" void kernel_launch(void* const* d_in, const int* in_sizes, int n_in,
                              void* d_out, int out_size, void* d_ws, size_t ws_size,
                              hipStream_t stream) {
    (void)in_sizes; (void)n_in; (void)out_size; (void)ws_size;
    const float* fS     = (const float*)d_in[0];
    const float* fT     = (const float*)d_in[1];
    const int*   target = (const int*)d_in[2];

    char* ws = (char*)d_ws;
    int*   labels = (int*)  (ws + OFF_LABELS);
    float* counts = (float*)(ws + OFF_COUNTS);
    float* meansS = (float*)(ws + OFF_SUMS_S);
    float* meansT = (float*)(ws + OFF_SUMS_T);
    float* normS  = (float*)(ws + OFF_NORM_S);
    float* normT  = (float*)(ws + OFF_NORM_T);
    float* part   = (float*)(ws + OFF_PART);
    // k_sums segment partials: temporal reuse of the OFF_PART region
    // (k_means consumes them before k_dots overwrites — same stream).
    float* partS  = (float*)(ws + OFF_PART);
    float* partT  = (float*)(ws + OFF_PART + PSEG_BYTES);

    hipMemsetAsync(d_out, 0, sizeof(float), stream);
    hipMemsetAsync(counts, 0, NB * NCLS * sizeof(float), stream);

    k_labels<<<NB * LBLK, 256, 0, stream>>>(target, labels, counts);
    k_sums  <<<NB * (NC / 2) * NSEG, 256, 0, stream>>>(fS, fT, labels, partS, partT);
    k_means <<<NB * NCLS, 64, 0, stream>>>(partS, partT, meansS, meansT, counts,
                                           normS, normT);
    k_dots  <<<NB * 16 * 8, 256, 0, stream>>>(fS, fT, meansS, meansT, labels, part);
    k_final <<<NB * NHW / 256, 256, 0, stream>>>(part, labels, normS, normT,
                                                 (float*)d_out);
}

// Round 7
// 195.177 us; speedup vs baseline: 1.6655x; 1.0399x over previous
//
#include <hip/hip_runtime.h>

// Problem constants (B=8, C=512, H=W=64, K=19 classes)
#define NCLS   19
#define NB     8
#define NC     512
#define NHW    4096      // 64*64
#define EPSM   1e-6f     // mean denominator eps
#define EPSC   1e-8f     // cosine eps
#define LBLK   8         // k_labels blocks per batch

// Workspace layout (bytes)
#define OFF_LABELS   0u          // int32 [NB*NHW]
#define OFF_COUNTS   131072u     // float [NB*NCLS] ([b][k])
#define OFF_SUMS_S   132096u     // float [NB][NCLS][NC]  (means S after k_means, in place)
#define OFF_SUMS_T   443392u     // float [NB][NCLS][NC]
#define OFF_NORM_S   754688u     // float [NB*NCLS]
#define OFF_NORM_T   755712u     // float [NB*NCLS]
#define OFF_PART     756736u     // float [4 arrays][8 chunks][NB*NHW] (k_dots partials)
// total = 756736 + 4*8*32768*4 = 4,951,040 B

// ---------------------------------------------------------------------------
// Wave-64 sum via DPP (VALU pipe only, no LDS). Result valid in lane 63.
template<int CTRL>
__device__ __forceinline__ float dpp_add(float x) {
    int y = __builtin_amdgcn_update_dpp(0, __float_as_int(x), CTRL, 0xf, 0xf, false);
    return x + __int_as_float(y);
}
__device__ __forceinline__ float wave64_sum(float x) {
    x = dpp_add<0x111>(x);   // row_shr:1
    x = dpp_add<0x112>(x);   // row_shr:2
    x = dpp_add<0x114>(x);   // row_shr:4
    x = dpp_add<0x118>(x);   // row_shr:8  -> lane15 of each row16 has row sum
    x = dpp_add<0x142>(x);   // row_bcast:15 -> lane31/63 have half sums
    x = dpp_add<0x143>(x);   // row_bcast:31 -> lane63 has total
    return x;
}

// ---------------------------------------------------------------------------
// Kernel 1: nearest-resize labels + per-batch class counts (64 blocks).
// Per-block LDS hist -> one float atomicAdd per (block,class); integer-valued
// f32 adds are exact and order-independent. counts zeroed by memset upstream.
__global__ __launch_bounds__(256) void k_labels(const int* __restrict__ target,
                                                int* __restrict__ labels,
                                                float* __restrict__ counts) {
    __shared__ int hist[NCLS];
    const int blk = blockIdx.x;          // 0..63
    const int b    = blk >> 3;
    const int part = blk & (LBLK - 1);   // 512-pixel slice
    const int t = threadIdx.x;
    if (t < NCLS) hist[t] = 0;
    __syncthreads();
    const int* tb = target + (size_t)b * 512 * 512;
    #pragma unroll
    for (int i = 0; i < 2; ++i) {
        int n = part * 512 + t + i * 256;
        int y = n >> 6, x = n & 63;
        int l = tb[(y * 8) * 512 + x * 8];   // in_idx = floor(out_idx*512/64)
        labels[b * NHW + n] = l;
        if (l >= 0 && l < NCLS) atomicAdd(&hist[l], 1);
    }
    __syncthreads();
    if (t < NCLS && hist[t] > 0)
        atomicAdd(&counts[b * NCLS + t], (float)hist[t]);
}

// ---------------------------------------------------------------------------
// Kernel 2: per-class channel sums via LDS COLUMN-PRIVATE accumulator.
//
// ALGORITHM HISTORY (load-bearing):
//   r0-r4/r6 mask-and-accumulate: O(NCLS)=19 cmp/sel/fma per element.
//     Measured invariant: ~57 us at occupancy 19% AND 57% (r4/r6) ->
//     instruction-stream-bound, not latency-bound. VALUBusy ~53%.
//   r5 LDS atomics: 174 us — colliding ds_add serializes PER-LANE on the
//     single LDS pipe (~204 cy/wave-atomic). Atomics are the poison.
//   This version: O(1)/element, NO atomics. acc[ten][k][t]: thread t owns
//     column t exclusively (no races); address === t (mod 32) -> every lane
//     its own bank for ANY label mix (2 lanes/bank = free, m136); same-lane
//     same-address RMWs are ordered by DS in-order execution.
//   Cost model: 33.5M RMW = 2 wave-LDS-ops/elem -> 4096/CU x ~6cy ~= 10 us
//     LDS-pipe, VALU ~3 us, L3-resident reads ~8 us (overlapped).
//
// Block = (b, channel c); 4096 blocks x 256 thr. LDS 38.9 KB -> 4 blocks/CU.
// Epilogue: tree-reduce 38 rows of 256, write sums[b][k][c] directly
// (block owns ALL pixels of (b,c) -> no partials, k_means in-place).
__global__ __launch_bounds__(256) void k_sums(const float* __restrict__ fS,
                                              const float* __restrict__ fT,
                                              const int* __restrict__ labels,
                                              float* __restrict__ sumsS,
                                              float* __restrict__ sumsT) {
    __shared__ float acc[2 * NCLS * 256];
    const int t   = threadIdx.x;
    const int blk = blockIdx.x;          // 0..4095
    const int b   = blk >> 9;            // 512 channels per batch
    const int c   = blk & (NC - 1);

    {   // zero LDS, vectorized: 2*19*64 = 2432 float4
        float4* av = (float4*)acc;
        const float4 z = make_float4(0.f, 0.f, 0.f, 0.f);
        for (int i = t; i < 2 * NCLS * 64; i += 256) av[i] = z;
    }
    __syncthreads();

    const int4*   lab4 = (const int4*)(labels + b * NHW);
    const float4* pS   = (const float4*)(fS + ((size_t)(b * NC) + c) * NHW);
    const float4* pT   = (const float4*)(fT + ((size_t)(b * NC) + c) * NHW);
    float* aS = acc + t;                 // row stride 256 floats: aS[k<<8]
    float* aT = acc + NCLS * 256 + t;

    #pragma unroll
    for (int i = 0; i < 4; ++i) {
        const int idx = t + (i << 8);    // float4 index (4 pixels), coalesced
        const int4   l  = lab4[idx];
        const float4 vS = pS[idx];
        const float4 vT = pT[idx];
        if ((unsigned)l.x < NCLS) { aS[l.x << 8] += vS.x; aT[l.x << 8] += vT.x; }
        if ((unsigned)l.y < NCLS) { aS[l.y << 8] += vS.y; aT[l.y << 8] += vT.y; }
        if ((unsigned)l.z < NCLS) { aS[l.z << 8] += vS.z; aT[l.z << 8] += vT.z; }
        if ((unsigned)l.w < NCLS) { aS[l.w << 8] += vS.w; aT[l.w << 8] += vT.w; }
    }
    __syncthreads();

    // Reduce 38 rows of 256 across threads; rows split round-robin over waves.
    // Row reads at addr (r*256+lane)*4 -> bank = lane%32, conflict-free.
    const int w = t >> 6, lane = t & 63;
    for (int r = w; r < 2 * NCLS; r += 4) {
        const float* row = acc + r * 256;
        float x = (row[lane] + row[lane + 64]) + (row[lane + 128] + row[lane + 192]);
        x = wave64_sum(x);
        if (lane == 63) {
            const int ten = (r >= NCLS) ? 1 : 0;
            const int k   = r - ten * NCLS;
            float* dst = (ten ? sumsT : sumsS) + ((size_t)(b * NCLS + k)) * NC + c;
            *dst = x;
        }
    }
}

// ---------------------------------------------------------------------------
// Kernel 3: means = sums/(count+eps) in place + per-(b,k) center norms.
// One wave per (b,k); sums layout [b][k][c] -> coalesced.
__global__ __launch_bounds__(64) void k_means(float* __restrict__ sumsS,
                                              float* __restrict__ sumsT,
                                              const float* __restrict__ counts,
                                              float* __restrict__ normS,
                                              float* __restrict__ normT) {
    const int bk = blockIdx.x;
    const int t = threadIdx.x;
    const float inv = 1.f / (counts[bk] + EPSM);
    float* rS = sumsS + (size_t)bk * NC;
    float* rT = sumsT + (size_t)bk * NC;
    float aS = 0.f, aT = 0.f;
    #pragma unroll
    for (int i = 0; i < NC / 64; ++i) {
        float mS = rS[t + i * 64] * inv; rS[t + i * 64] = mS; aS += mS * mS;
        float mT = rT[t + i * 64] * inv; rT[t + i * 64] = mT; aT += mT * mT;
    }
    aS = wave64_sum(aS);
    aT = wave64_sum(aT);
    if (t == 63) { normS[bk] = sqrtf(aS); normT[bk] = sqrtf(aT); }
}

// ---------------------------------------------------------------------------
// Kernel 4: per-pixel dot(f, mean[lab]) and ||f||^2, atomic-free.
// Grid: 8 b x 16 pixel-tiles x 8 c-chunks = 1024 blocks.
// Means tile in LDS as [class][65] -> gather bank = (l+ci)%32, conflict-free.
#define CCH 64
__global__ __launch_bounds__(256) void k_dots(const float* __restrict__ fS,
                                              const float* __restrict__ fT,
                                              const float* __restrict__ meansS,
                                              const float* __restrict__ meansT,
                                              const int* __restrict__ labels,
                                              float* __restrict__ part) {
    __shared__ float mS[NCLS * 65];
    __shared__ float mT[NCLS * 65];
    const int blk = blockIdx.x;
    const int chunk = blk & 7;
    const int tile  = (blk >> 3) & 15;
    const int b     = blk >> 7;
    const int t = threadIdx.x;
    const int c0 = chunk * CCH;
    const int n = tile * 256 + t;

    for (int i = t; i < NCLS * CCH; i += 256) {
        const int k = i >> 6, j = i & 63;
        mS[k * 65 + j] = meansS[((size_t)(b * NCLS + k)) * NC + c0 + j];
        mT[k * 65 + j] = meansT[((size_t)(b * NCLS + k)) * NC + c0 + j];
    }
    __syncthreads();

    const int l = labels[b * NHW + n];
    const int lc = (l >= 0 && l < NCLS) ? l : 0;
    const float* pS = fS + ((size_t)(b * NC + c0)) * NHW + n;
    const float* pT = fT + ((size_t)(b * NC + c0)) * NHW + n;
    float dS = 0.f, nS = 0.f, dT = 0.f, nT = 0.f;
    #pragma unroll 8
    for (int ci = 0; ci < CCH; ++ci) {
        const float vS = pS[(size_t)ci * NHW];
        const float vT = pT[(size_t)ci * NHW];
        const float ms = mS[lc * 65 + ci];
        const float mt = mT[lc * 65 + ci];
        dS += vS * ms; nS += vS * vS;
        dT += vT * mt; nT += vT * vT;
    }
    const int p = b * NHW + n;
    part[((size_t)(0 * 8 + chunk)) * (NB * NHW) + p] = dS;
    part[((size_t)(1 * 8 + chunk)) * (NB * NHW) + p] = nS;
    part[((size_t)(2 * 8 + chunk)) * (NB * NHW) + p] = dT;
    part[((size_t)(3 * 8 + chunk)) * (NB * NHW) + p] = nT;
}

// ---------------------------------------------------------------------------
// Kernel 5: combine partials, cosines, MSE reduce.
__global__ __launch_bounds__(256) void k_final(const float* __restrict__ part,
                                               const int* __restrict__ labels,
                                               const float* __restrict__ normS,
                                               const float* __restrict__ normT,
                                               float* __restrict__ out) {
    __shared__ float red[4];
    const int p = blockIdx.x * 256 + threadIdx.x;
    const int b = p >> 12;
    float dS = 0.f, nS = 0.f, dT = 0.f, nT = 0.f;
    #pragma unroll
    for (int ch = 0; ch < 8; ++ch) {
        dS += part[((size_t)(0 * 8 + ch)) * (NB * NHW) + p];
        nS += part[((size_t)(1 * 8 + ch)) * (NB * NHW) + p];
        dT += part[((size_t)(2 * 8 + ch)) * (NB * NHW) + p];
        nT += part[((size_t)(3 * 8 + ch)) * (NB * NHW) + p];
    }
    const int l = labels[p];
    float val = 0.f;
    if (l >= 0 && l < NCLS) {
        float cS = dS / (fmaxf(sqrtf(nS), EPSC) * fmaxf(normS[b * NCLS + l], EPSC));
        float cT = dT / (fmaxf(sqrtf(nT), EPSC) * fmaxf(normT[b * NCLS + l], EPSC));
        float d = cS - cT;
        val = d * d;
    }
    val = wave64_sum(val);
    if ((threadIdx.x & 63) == 63) red[threadIdx.x >> 6] = val;
    __syncthreads();
    if (threadIdx.x == 0)
        atomicAdd(out, (red[0] + red[1] + red[2] + red[3]) * (1.f / (NB * NHW)));
}

// ---------------------------------------------------------------------------
extern "C" void kernel_launch(void* const* d_in, const int* in_sizes, int n_in,
                              void* d_out, int out_size, void* d_ws, size_t ws_size,
                              hipStream_t stream) {
    (void)in_sizes; (void)n_in; (void)out_size; (void)ws_size;
    const float* fS     = (const float*)d_in[0];
    const float* fT     = (const float*)d_in[1];
    const int*   target = (const int*)d_in[2];

    char* ws = (char*)d_ws;
    int*   labels = (int*)  (ws + OFF_LABELS);
    float* counts = (float*)(ws + OFF_COUNTS);
    float* sumsS  = (float*)(ws + OFF_SUMS_S);   // means after k_means (in place)
    float* sumsT  = (float*)(ws + OFF_SUMS_T);
    float* normS  = (float*)(ws + OFF_NORM_S);
    float* normT  = (float*)(ws + OFF_NORM_T);
    float* part   = (float*)(ws + OFF_PART);

    hipMemsetAsync(d_out, 0, sizeof(float), stream);
    hipMemsetAsync(counts, 0, NB * NCLS * sizeof(float), stream);

    k_labels<<<NB * LBLK, 256, 0, stream>>>(target, labels, counts);
    k_sums  <<<NB * NC, 256, 0, stream>>>(fS, fT, labels, sumsS, sumsT);
    k_means <<<NB * NCLS, 64, 0, stream>>>(sumsS, sumsT, counts, normS, normT);
    k_dots  <<<NB * 16 * 8, 256, 0, stream>>>(fS, fT, sumsS, sumsT, labels, part);
    k_final <<<NB * NHW / 256, 256, 0, stream>>>(part, labels, normS, normT,
                                                 (float*)d_out);
}

// Round 8
// 193.387 us; speedup vs baseline: 1.6810x; 1.0093x over previous
//
#include <hip/hip_runtime.h>

// Problem constants (B=8, C=512, H=W=64, K=19 classes)
#define NCLS   19
#define NB     8
#define NC     512
#define NHW    4096      // 64*64
#define EPSM   1e-6f     // mean denominator eps
#define EPSC   1e-8f     // cosine eps
#define LBLK   8         // k_labels blocks per batch

// Workspace layout (bytes)
#define OFF_LABELS   0u          // int32 [NB*NHW]
#define OFF_COUNTS   131072u     // float [NB*NCLS] ([b][k])
#define OFF_SUMS_S   132096u     // float [NB][NCLS][NC]  (means S after k_means, in place)
#define OFF_SUMS_T   443392u     // float [NB][NCLS][NC]
#define OFF_NORM_S   754688u     // float [NB*NCLS]
#define OFF_NORM_T   755712u     // float [NB*NCLS]
#define OFF_PART     756736u     // float [4 arrays][8 chunks][NB*NHW] (k_dots partials)
// total = 756736 + 4*8*32768*4 = 4,951,040 B

// ---------------------------------------------------------------------------
// Wave-64 sum via DPP (VALU pipe only, no LDS). Result valid in lane 63.
template<int CTRL>
__device__ __forceinline__ float dpp_add(float x) {
    int y = __builtin_amdgcn_update_dpp(0, __float_as_int(x), CTRL, 0xf, 0xf, false);
    return x + __int_as_float(y);
}
__device__ __forceinline__ float wave64_sum(float x) {
    x = dpp_add<0x111>(x);   // row_shr:1
    x = dpp_add<0x112>(x);   // row_shr:2
    x = dpp_add<0x114>(x);   // row_shr:4
    x = dpp_add<0x118>(x);   // row_shr:8  -> lane15 of each row16 has row sum
    x = dpp_add<0x142>(x);   // row_bcast:15 -> lane31/63 have half sums
    x = dpp_add<0x143>(x);   // row_bcast:31 -> lane63 has total
    return x;
}

// ---------------------------------------------------------------------------
// Kernel 1: nearest-resize labels + per-batch class counts (64 blocks).
// Per-block LDS hist -> one float atomicAdd per (block,class); integer-valued
// f32 adds are exact and order-independent. counts zeroed by memset upstream.
__global__ __launch_bounds__(256) void k_labels(const int* __restrict__ target,
                                                int* __restrict__ labels,
                                                float* __restrict__ counts) {
    __shared__ int hist[NCLS];
    const int blk = blockIdx.x;          // 0..63
    const int b    = blk >> 3;
    const int part = blk & (LBLK - 1);   // 512-pixel slice
    const int t = threadIdx.x;
    if (t < NCLS) hist[t] = 0;
    __syncthreads();
    const int* tb = target + (size_t)b * 512 * 512;
    #pragma unroll
    for (int i = 0; i < 2; ++i) {
        int n = part * 512 + t + i * 256;
        int y = n >> 6, x = n & 63;
        int l = tb[(y * 8) * 512 + x * 8];   // in_idx = floor(out_idx*512/64)
        labels[b * NHW + n] = l;
        if (l >= 0 && l < NCLS) atomicAdd(&hist[l], 1);
    }
    __syncthreads();
    if (t < NCLS && hist[t] > 0)
        atomicAdd(&counts[b * NCLS + t], (float)hist[t]);
}

// ---------------------------------------------------------------------------
// Kernel 2: per-class channel sums via LDS column-private accumulator,
// S+T PACKED AS float2 (one b64 RMW per element instead of two b32 RMWs).
//
// ALGORITHM HISTORY (load-bearing):
//   r0-r4/r6 mask-and-accumulate: O(19) cmp/sel/fma per element -> ~57 us
//     VALU-issue floor (invariant across occupancy 19%..57%).
//   r5 LDS atomics: 174 us — colliding ds_add serializes PER-LANE (~204
//     cy/wave-atomic). Atomics are the poison; do not revisit.
//   r7 column-private scatter (separate S,T b32 RMWs): 51 us. DS-throughput
//     model said ~18; the 2.75x gap is the read->add->write chain stalls
//     (64 DS ops + 32 chains per thread).
//   THIS VERSION: acc[k][t] is float2 (.x=S, .y=T) -> ONE ds_read_b64 +
//     ONE ds_write_b64 per element. DS ops AND chains halve (32 ops,
//     16 chains per thread). Same 38912 B LDS, same occupancy, VGPR ~52.
//   Correctness: thread t owns column t exclusively (no races); same-wave
//     DS ops execute in-order (RAW through LDS safe without waitcnt);
//     bank map for b64: lane L -> bank pair (2L)%32, 4 lanes/pair = the
//     natural 512B/instr minimum, label-independent.
//
// Block = (b, channel c); 4096 blocks x 256 thr; 4 blocks/CU (LDS-limited).
// Epilogue: reduce 19 float2-rows of 256, write sums[b][k][c] directly.
__global__ __launch_bounds__(256) void k_sums(const float* __restrict__ fS,
                                              const float* __restrict__ fT,
                                              const int* __restrict__ labels,
                                              float* __restrict__ sumsS,
                                              float* __restrict__ sumsT) {
    __shared__ float2 acc[NCLS * 256];   // 38912 B
    const int t   = threadIdx.x;
    const int blk = blockIdx.x;          // 0..4095
    const int b   = blk >> 9;            // 512 channels per batch
    const int c   = blk & (NC - 1);

    {   // zero LDS, vectorized: 19*256*8B / 16B = 2432 float4
        float4* av = (float4*)acc;
        const float4 z = make_float4(0.f, 0.f, 0.f, 0.f);
        for (int i = t; i < NCLS * 128; i += 256) av[i] = z;
    }
    __syncthreads();

    const int4*   lab4 = (const int4*)(labels + b * NHW);
    const float4* pS   = (const float4*)(fS + ((size_t)(b * NC) + c) * NHW);
    const float4* pT   = (const float4*)(fT + ((size_t)(b * NC) + c) * NHW);
    float2* a0 = acc + t;                // element k at a0[k<<8]

    #pragma unroll
    for (int i = 0; i < 4; ++i) {
        const int idx = t + (i << 8);    // float4 index (4 pixels), coalesced
        const int4   l  = lab4[idx];
        const float4 vS = pS[idx];
        const float4 vT = pT[idx];
        if ((unsigned)l.x < NCLS) { float2 v = a0[l.x << 8]; v.x += vS.x; v.y += vT.x; a0[l.x << 8] = v; }
        if ((unsigned)l.y < NCLS) { float2 v = a0[l.y << 8]; v.x += vS.y; v.y += vT.y; a0[l.y << 8] = v; }
        if ((unsigned)l.z < NCLS) { float2 v = a0[l.z << 8]; v.x += vS.z; v.y += vT.z; a0[l.z << 8] = v; }
        if ((unsigned)l.w < NCLS) { float2 v = a0[l.w << 8]; v.x += vS.w; v.y += vT.w; a0[l.w << 8] = v; }
    }
    __syncthreads();

    // Reduce 19 float2-rows of 256; rows round-robin over the 4 waves.
    const int w = t >> 6, lane = t & 63;
    for (int r = w; r < NCLS; r += 4) {
        const float2* row = acc + r * 256;
        const float2 p0 = row[lane], p1 = row[lane + 64];
        const float2 p2 = row[lane + 128], p3 = row[lane + 192];
        float sx = (p0.x + p1.x) + (p2.x + p3.x);
        float sy = (p0.y + p1.y) + (p2.y + p3.y);
        sx = wave64_sum(sx);
        sy = wave64_sum(sy);
        if (lane == 63) {
            sumsS[((size_t)(b * NCLS + r)) * NC + c] = sx;
            sumsT[((size_t)(b * NCLS + r)) * NC + c] = sy;
        }
    }
}

// ---------------------------------------------------------------------------
// Kernel 3: means = sums/(count+eps) in place + per-(b,k) center norms.
// One wave per (b,k); sums layout [b][k][c] -> coalesced.
__global__ __launch_bounds__(64) void k_means(float* __restrict__ sumsS,
                                              float* __restrict__ sumsT,
                                              const float* __restrict__ counts,
                                              float* __restrict__ normS,
                                              float* __restrict__ normT) {
    const int bk = blockIdx.x;
    const int t = threadIdx.x;
    const float inv = 1.f / (counts[bk] + EPSM);
    float* rS = sumsS + (size_t)bk * NC;
    float* rT = sumsT + (size_t)bk * NC;
    float aS = 0.f, aT = 0.f;
    #pragma unroll
    for (int i = 0; i < NC / 64; ++i) {
        float mS = rS[t + i * 64] * inv; rS[t + i * 64] = mS; aS += mS * mS;
        float mT = rT[t + i * 64] * inv; rT[t + i * 64] = mT; aT += mT * mT;
    }
    aS = wave64_sum(aS);
    aT = wave64_sum(aT);
    if (t == 63) { normS[bk] = sqrtf(aS); normT[bk] = sqrtf(aT); }
}

// ---------------------------------------------------------------------------
// Kernel 4: per-pixel dot(f, mean[lab]) and ||f||^2, atomic-free.
// Grid: 8 b x 16 pixel-tiles x 8 c-chunks = 1024 blocks.
// Means tile in LDS as [class][65] -> gather bank = (l+ci)%32, conflict-free.
#define CCH 64
__global__ __launch_bounds__(256) void k_dots(const float* __restrict__ fS,
                                              const float* __restrict__ fT,
                                              const float* __restrict__ meansS,
                                              const float* __restrict__ meansT,
                                              const int* __restrict__ labels,
                                              float* __restrict__ part) {
    __shared__ float mS[NCLS * 65];
    __shared__ float mT[NCLS * 65];
    const int blk = blockIdx.x;
    const int chunk = blk & 7;
    const int tile  = (blk >> 3) & 15;
    const int b     = blk >> 7;
    const int t = threadIdx.x;
    const int c0 = chunk * CCH;
    const int n = tile * 256 + t;

    for (int i = t; i < NCLS * CCH; i += 256) {
        const int k = i >> 6, j = i & 63;
        mS[k * 65 + j] = meansS[((size_t)(b * NCLS + k)) * NC + c0 + j];
        mT[k * 65 + j] = meansT[((size_t)(b * NCLS + k)) * NC + c0 + j];
    }
    __syncthreads();

    const int l = labels[b * NHW + n];
    const int lc = (l >= 0 && l < NCLS) ? l : 0;
    const float* pS = fS + ((size_t)(b * NC + c0)) * NHW + n;
    const float* pT = fT + ((size_t)(b * NC + c0)) * NHW + n;
    float dS = 0.f, nS = 0.f, dT = 0.f, nT = 0.f;
    #pragma unroll 8
    for (int ci = 0; ci < CCH; ++ci) {
        const float vS = pS[(size_t)ci * NHW];
        const float vT = pT[(size_t)ci * NHW];
        const float ms = mS[lc * 65 + ci];
        const float mt = mT[lc * 65 + ci];
        dS += vS * ms; nS += vS * vS;
        dT += vT * mt; nT += vT * vT;
    }
    const int p = b * NHW + n;
    part[((size_t)(0 * 8 + chunk)) * (NB * NHW) + p] = dS;
    part[((size_t)(1 * 8 + chunk)) * (NB * NHW) + p] = nS;
    part[((size_t)(2 * 8 + chunk)) * (NB * NHW) + p] = dT;
    part[((size_t)(3 * 8 + chunk)) * (NB * NHW) + p] = nT;
}

// ---------------------------------------------------------------------------
// Kernel 5: combine partials, cosines, MSE reduce.
__global__ __launch_bounds__(256) void k_final(const float* __restrict__ part,
                                               const int* __restrict__ labels,
                                               const float* __restrict__ normS,
                                               const float* __restrict__ normT,
                                               float* __restrict__ out) {
    __shared__ float red[4];
    const int p = blockIdx.x * 256 + threadIdx.x;
    const int b = p >> 12;
    float dS = 0.f, nS = 0.f, dT = 0.f, nT = 0.f;
    #pragma unroll
    for (int ch = 0; ch < 8; ++ch) {
        dS += part[((size_t)(0 * 8 + ch)) * (NB * NHW) + p];
        nS += part[((size_t)(1 * 8 + ch)) * (NB * NHW) + p];
        dT += part[((size_t)(2 * 8 + ch)) * (NB * NHW) + p];
        nT += part[((size_t)(3 * 8 + ch)) * (NB * NHW) + p];
    }
    const int l = labels[p];
    float val = 0.f;
    if (l >= 0 && l < NCLS) {
        float cS = dS / (fmaxf(sqrtf(nS), EPSC) * fmaxf(normS[b * NCLS + l], EPSC));
        float cT = dT / (fmaxf(sqrtf(nT), EPSC) * fmaxf(normT[b * NCLS + l], EPSC));
        float d = cS - cT;
        val = d * d;
    }
    val = wave64_sum(val);
    if ((threadIdx.x & 63) == 63) red[threadIdx.x >> 6] = val;
    __syncthreads();
    if (threadIdx.x == 0)
        atomicAdd(out, (red[0] + red[1] + red[2] + red[3]) * (1.f / (NB * NHW)));
}

// ---------------------------------------------------------------------------
extern "C" void kernel_launch(void* const* d_in, const int* in_sizes, int n_in,
                              void* d_out, int out_size, void* d_ws, size_t ws_size,
                              hipStream_t stream) {
    (void)in_sizes; (void)n_in; (void)out_size; (void)ws_size;
    const float* fS     = (const float*)d_in[0];
    const float* fT     = (const float*)d_in[1];
    const int*   target = (const int*)d_in[2];

    char* ws = (char*)d_ws;
    int*   labels = (int*)  (ws + OFF_LABELS);
    float* counts = (float*)(ws + OFF_COUNTS);
    float* sumsS  = (float*)(ws + OFF_SUMS_S);   // means after k_means (in place)
    float* sumsT  = (float*)(ws + OFF_SUMS_T);
    float* normS  = (float*)(ws + OFF_NORM_S);
    float* normT  = (float*)(ws + OFF_NORM_T);
    float* part   = (float*)(ws + OFF_PART);

    hipMemsetAsync(d_out, 0, sizeof(float), stream);
    hipMemsetAsync(counts, 0, NB * NCLS * sizeof(float), stream);

    k_labels<<<NB * LBLK, 256, 0, stream>>>(target, labels, counts);
    k_sums  <<<NB * NC, 256, 0, stream>>>(fS, fT, labels, sumsS, sumsT);
    k_means <<<NB * NCLS, 64, 0, stream>>>(sumsS, sumsT, counts, normS, normT);
    k_dots  <<<NB * 16 * 8, 256, 0, stream>>>(fS, fT, sumsS, sumsT, labels, part);
    k_final <<<NB * NHW / 256, 256, 0, stream>>>(part, labels, normS, normT,
                                                 (float*)d_out);
}

// Round 10
// 189.296 us; speedup vs baseline: 1.7173x; 1.0216x over previous
//
#include <hip/hip_runtime.h>

// Problem constants (B=8, C=512, H=W=64, K=19 classes)
#define NCLS   19
#define NB     8
#define NC     512
#define NHW    4096      // 64*64
#define EPSM   1e-6f     // mean denominator eps
#define EPSC   1e-8f     // cosine eps
#define LBLK   8         // k_labels blocks per batch

// Workspace layout (bytes)
#define OFF_LABELS   0u          // int32 [NB*NHW]
#define OFF_COUNTS   131072u     // float [NB*NCLS] ([b][k])
#define OFF_SUMS_S   132096u     // float [NB][NCLS][NC]  (means S after k_means, in place)
#define OFF_SUMS_T   443392u     // float [NB][NCLS][NC]
#define OFF_NORM_S   754688u     // float [NB*NCLS]
#define OFF_NORM_T   755712u     // float [NB*NCLS]
#define OFF_PART     756736u     // float [4 arrays][8 chunks][NB*NHW] (k_dots partials)
// total = 756736 + 4*8*32768*4 = 4,951,040 B

// ---------------------------------------------------------------------------
// Wave-64 sum via DPP (VALU pipe only, no LDS). Result valid in lane 63.
template<int CTRL>
__device__ __forceinline__ float dpp_add(float x) {
    int y = __builtin_amdgcn_update_dpp(0, __float_as_int(x), CTRL, 0xf, 0xf, false);
    return x + __int_as_float(y);
}
__device__ __forceinline__ float wave64_sum(float x) {
    x = dpp_add<0x111>(x);   // row_shr:1
    x = dpp_add<0x112>(x);   // row_shr:2
    x = dpp_add<0x114>(x);   // row_shr:4
    x = dpp_add<0x118>(x);   // row_shr:8  -> lane15 of each row16 has row sum
    x = dpp_add<0x142>(x);   // row_bcast:15 -> lane31/63 have half sums
    x = dpp_add<0x143>(x);   // row_bcast:31 -> lane63 has total
    return x;
}

// ---------------------------------------------------------------------------
// Kernel 1: nearest-resize labels + per-batch class counts (64 blocks).
// Per-block LDS hist -> one float atomicAdd per (block,class); integer-valued
// f32 adds are exact and order-independent. counts zeroed by memset upstream.
__global__ __launch_bounds__(256) void k_labels(const int* __restrict__ target,
                                                int* __restrict__ labels,
                                                float* __restrict__ counts) {
    __shared__ int hist[NCLS];
    const int blk = blockIdx.x;          // 0..63
    const int b    = blk >> 3;
    const int part = blk & (LBLK - 1);   // 512-pixel slice
    const int t = threadIdx.x;
    if (t < NCLS) hist[t] = 0;
    __syncthreads();
    const int* tb = target + (size_t)b * 512 * 512;
    #pragma unroll
    for (int i = 0; i < 2; ++i) {
        int n = part * 512 + t + i * 256;
        int y = n >> 6, x = n & 63;
        int l = tb[(y * 8) * 512 + x * 8];   // in_idx = floor(out_idx*512/64)
        labels[b * NHW + n] = l;
        if (l >= 0 && l < NCLS) atomicAdd(&hist[l], 1);
    }
    __syncthreads();
    if (t < NCLS && hist[t] > 0)
        atomicAdd(&counts[b * NCLS + t], (float)hist[t]);
}

// ---------------------------------------------------------------------------
// Kernel 2: per-class channel sums, LDS column-private float2 accumulator,
// with REGISTER-PIPELINED loads (this round's single variable; resubmission —
// round 9 bench was an infra failure, experiment never measured).
//
// ALGORITHM HISTORY (load-bearing):
//   r0-r4/r6 mask-accumulate O(19)/elem: ~57 us VALU floor.
//   r5 LDS atomics: 174 us (colliding ds_add serializes per-lane). Poison.
//   r7 column scatter b32: 51 us.  r8 packed float2 b64: 48.6 us.
//   r8 falsified the DS-chain theory (DS ops halved, -5% only). Remaining
//   invariant: 128 MB feature read at ~2.7 TB/s effective (1.47 HBM + L3).
//   VGPR=52 meant only ~2-3 of the 12 float4 loads could be in flight ->
//   each iteration eats a full L3/HBM round-trip (demand-latency theory).
// THIS VERSION: labels batch-loaded up front (L2-hot); S/T prefetched one
//   iteration ahead; first loads issued BEFORE the LDS-zero loop so their
//   latency hides under zeroing+barrier. VGPR ~76 (<128 keeps 4 waves/SIMD).
// DECISIVE: ~35 us -> latency-limited confirmed; ~48 us -> 2.7 TB/s
//   pattern-wall confirmed by exclusion, k_sums at roofline.
//
// Block = (b, channel c); 4096 blocks x 256 thr; 4 blocks/CU (LDS 38912 B).
__global__ __launch_bounds__(256) void k_sums(const float* __restrict__ fS,
                                              const float* __restrict__ fT,
                                              const int* __restrict__ labels,
                                              float* __restrict__ sumsS,
                                              float* __restrict__ sumsT) {
    __shared__ float2 acc[NCLS * 256];   // 38912 B
    const int t   = threadIdx.x;
    const int blk = blockIdx.x;          // 0..4095
    const int b   = blk >> 9;            // 512 channels per batch
    const int c   = blk & (NC - 1);

    const int4*   lab4 = (const int4*)(labels + b * NHW);
    const float4* pS   = (const float4*)(fS + ((size_t)(b * NC) + c) * NHW);
    const float4* pT   = (const float4*)(fT + ((size_t)(b * NC) + c) * NHW);

    // Issue first feature loads + all label loads BEFORE zeroing: their
    // ~700-900 cy latency hides under the zero loop + barrier.
    int4 lab[4];
    #pragma unroll
    for (int j = 0; j < 4; ++j) lab[j] = lab4[t + (j << 8)];
    float4 curS = pS[t];
    float4 curT = pT[t];

    {   // zero LDS, vectorized: 19*256*8B / 16B = 2432 float4
        float4* av = (float4*)acc;
        const float4 z = make_float4(0.f, 0.f, 0.f, 0.f);
        for (int i = t; i < NCLS * 128; i += 256) av[i] = z;
    }
    __syncthreads();

    float2* a0 = acc + t;                // element k at a0[k<<8]

    #pragma unroll
    for (int i = 0; i < 4; ++i) {
        float4 nxtS, nxtT;
        if (i < 3) {                     // prefetch next iteration (depth 1)
            nxtS = pS[t + ((i + 1) << 8)];
            nxtT = pT[t + ((i + 1) << 8)];
        }
        const int4 l = lab[i];
        if ((unsigned)l.x < NCLS) { float2 v = a0[l.x << 8]; v.x += curS.x; v.y += curT.x; a0[l.x << 8] = v; }
        if ((unsigned)l.y < NCLS) { float2 v = a0[l.y << 8]; v.x += curS.y; v.y += curT.y; a0[l.y << 8] = v; }
        if ((unsigned)l.z < NCLS) { float2 v = a0[l.z << 8]; v.x += curS.z; v.y += curT.z; a0[l.z << 8] = v; }
        if ((unsigned)l.w < NCLS) { float2 v = a0[l.w << 8]; v.x += curS.w; v.y += curT.w; a0[l.w << 8] = v; }
        if (i < 3) { curS = nxtS; curT = nxtT; }
    }
    __syncthreads();

    // Reduce 19 float2-rows of 256; rows round-robin over the 4 waves.
    const int w = t >> 6, lane = t & 63;
    for (int r = w; r < NCLS; r += 4) {
        const float2* row = acc + r * 256;
        const float2 p0 = row[lane], p1 = row[lane + 64];
        const float2 p2 = row[lane + 128], p3 = row[lane + 192];
        float sx = (p0.x + p1.x) + (p2.x + p3.x);
        float sy = (p0.y + p1.y) + (p2.y + p3.y);
        sx = wave64_sum(sx);
        sy = wave64_sum(sy);
        if (lane == 63) {
            sumsS[((size_t)(b * NCLS + r)) * NC + c] = sx;
            sumsT[((size_t)(b * NCLS + r)) * NC + c] = sy;
        }
    }
}

// ---------------------------------------------------------------------------
// Kernel 3: means = sums/(count+eps) in place + per-(b,k) center norms.
// One wave per (b,k); sums layout [b][k][c] -> coalesced.
__global__ __launch_bounds__(64) void k_means(float* __restrict__ sumsS,
                                              float* __restrict__ sumsT,
                                              const float* __restrict__ counts,
                                              float* __restrict__ normS,
                                              float* __restrict__ normT) {
    const int bk = blockIdx.x;
    const int t = threadIdx.x;
    const float inv = 1.f / (counts[bk] + EPSM);
    float* rS = sumsS + (size_t)bk * NC;
    float* rT = sumsT + (size_t)bk * NC;
    float aS = 0.f, aT = 0.f;
    #pragma unroll
    for (int i = 0; i < NC / 64; ++i) {
        float mS = rS[t + i * 64] * inv; rS[t + i * 64] = mS; aS += mS * mS;
        float mT = rT[t + i * 64] * inv; rT[t + i * 64] = mT; aT += mT * mT;
    }
    aS = wave64_sum(aS);
    aT = wave64_sum(aT);
    if (t == 63) { normS[bk] = sqrtf(aS); normT[bk] = sqrtf(aT); }
}

// ---------------------------------------------------------------------------
// Kernel 4: per-pixel dot(f, mean[lab]) and ||f||^2, atomic-free.
// Grid: 8 b x 16 pixel-tiles x 8 c-chunks = 1024 blocks.
// Means tile in LDS as [class][65] -> gather bank = (l+ci)%32, conflict-free.
#define CCH 64
__global__ __launch_bounds__(256) void k_dots(const float* __restrict__ fS,
                                              const float* __restrict__ fT,
                                              const float* __restrict__ meansS,
                                              const float* __restrict__ meansT,
                                              const int* __restrict__ labels,
                                              float* __restrict__ part) {
    __shared__ float mS[NCLS * 65];
    __shared__ float mT[NCLS * 65];
    const int blk = blockIdx.x;
    const int chunk = blk & 7;
    const int tile  = (blk >> 3) & 15;
    const int b     = blk >> 7;
    const int t = threadIdx.x;
    const int c0 = chunk * CCH;
    const int n = tile * 256 + t;

    for (int i = t; i < NCLS * CCH; i += 256) {
        const int k = i >> 6, j = i & 63;
        mS[k * 65 + j] = meansS[((size_t)(b * NCLS + k)) * NC + c0 + j];
        mT[k * 65 + j] = meansT[((size_t)(b * NCLS + k)) * NC + c0 + j];
    }
    __syncthreads();

    const int l = labels[b * NHW + n];
    const int lc = (l >= 0 && l < NCLS) ? l : 0;
    const float* pS = fS + ((size_t)(b * NC + c0)) * NHW + n;
    const float* pT = fT + ((size_t)(b * NC + c0)) * NHW + n;
    float dS = 0.f, nS = 0.f, dT = 0.f, nT = 0.f;
    #pragma unroll 8
    for (int ci = 0; ci < CCH; ++ci) {
        const float vS = pS[(size_t)ci * NHW];
        const float vT = pT[(size_t)ci * NHW];
        const float ms = mS[lc * 65 + ci];
        const float mt = mT[lc * 65 + ci];
        dS += vS * ms; nS += vS * vS;
        dT += vT * mt; nT += vT * vT;
    }
    const int p = b * NHW + n;
    part[((size_t)(0 * 8 + chunk)) * (NB * NHW) + p] = dS;
    part[((size_t)(1 * 8 + chunk)) * (NB * NHW) + p] = nS;
    part[((size_t)(2 * 8 + chunk)) * (NB * NHW) + p] = dT;
    part[((size_t)(3 * 8 + chunk)) * (NB * NHW) + p] = nT;
}

// ---------------------------------------------------------------------------
// Kernel 5: combine partials, cosines, MSE reduce.
__global__ __launch_bounds__(256) void k_final(const float* __restrict__ part,
                                               const int* __restrict__ labels,
                                               const float* __restrict__ normS,
                                               const float* __restrict__ normT,
                                               float* __restrict__ out) {
    __shared__ float red[4];
    const int p = blockIdx.x * 256 + threadIdx.x;
    const int b = p >> 12;
    float dS = 0.f, nS = 0.f, dT = 0.f, nT = 0.f;
    #pragma unroll
    for (int ch = 0; ch < 8; ++ch) {
        dS += part[((size_t)(0 * 8 + ch)) * (NB * NHW) + p];
        nS += part[((size_t)(1 * 8 + ch)) * (NB * NHW) + p];
        dT += part[((size_t)(2 * 8 + ch)) * (NB * NHW) + p];
        nT += part[((size_t)(3 * 8 + ch)) * (NB * NHW) + p];
    }
    const int l = labels[p];
    float val = 0.f;
    if (l >= 0 && l < NCLS) {
        float cS = dS / (fmaxf(sqrtf(nS), EPSC) * fmaxf(normS[b * NCLS + l], EPSC));
        float cT = dT / (fmaxf(sqrtf(nT), EPSC) * fmaxf(normT[b * NCLS + l], EPSC));
        float d = cS - cT;
        val = d * d;
    }
    val = wave64_sum(val);
    if ((threadIdx.x & 63) == 63) red[threadIdx.x >> 6] = val;
    __syncthreads();
    if (threadIdx.x == 0)
        atomicAdd(out, (red[0] + red[1] + red[2] + red[3]) * (1.f / (NB * NHW)));
}

// ---------------------------------------------------------------------------
extern "C" void kernel_launch(void* const* d_in, const int* in_sizes, int n_in,
                              void* d_out, int out_size, void* d_ws, size_t ws_size,
                              hipStream_t stream) {
    (void)in_sizes; (void)n_in; (void)out_size; (void)ws_size;
    const float* fS     = (const float*)d_in[0];
    const float* fT     = (const float*)d_in[1];
    const int*   target = (const int*)d_in[2];

    char* ws = (char*)d_ws;
    int*   labels = (int*)  (ws + OFF_LABELS);
    float* counts = (float*)(ws + OFF_COUNTS);
    float* sumsS  = (float*)(ws + OFF_SUMS_S);   // means after k_means (in place)
    float* sumsT  = (float*)(ws + OFF_SUMS_T);
    float* normS  = (float*)(ws + OFF_NORM_S);
    float* normT  = (float*)(ws + OFF_NORM_T);
    float* part   = (float*)(ws + OFF_PART);

    hipMemsetAsync(d_out, 0, sizeof(float), stream);
    hipMemsetAsync(counts, 0, NB * NCLS * sizeof(float), stream);

    k_labels<<<NB * LBLK, 256, 0, stream>>>(target, labels, counts);
    k_sums  <<<NB * NC, 256, 0, stream>>>(fS, fT, labels, sumsS, sumsT);
    k_means <<<NB * NCLS, 64, 0, stream>>>(sumsS, sumsT, counts, normS, normT);
    k_dots  <<<NB * 16 * 8, 256, 0, stream>>>(fS, fT, sumsS, sumsT, labels, part);
    k_final <<<NB * NHW / 256, 256, 0, stream>>>(part, labels, normS, normT,
                                                 (float*)d_out);
}

// Round 11
// 189.085 us; speedup vs baseline: 1.7192x; 1.0011x over previous
//
#include <hip/hip_runtime.h>

// Problem constants (B=8, C=512, H=W=64, K=19 classes)
#define NCLS   19
#define NB     8
#define NC     512
#define NHW    4096      // 64*64
#define EPSM   1e-6f     // mean denominator eps
#define EPSC   1e-8f     // cosine eps
#define LBLK   8         // k_labels blocks per batch

// Workspace layout (bytes)
#define OFF_LABELS   0u          // int32 [NB*NHW]
#define OFF_COUNTS   131072u     // float [NB*NCLS] ([b][k])
#define OFF_SUMS_S   132096u     // float [NB][NCLS][NC]  (means S after k_means, in place)
#define OFF_SUMS_T   443392u     // float [NB][NCLS][NC]
#define OFF_NORM_S   754688u     // float [NB*NCLS]
#define OFF_NORM_T   755712u     // float [NB*NCLS]
#define OFF_PART     756736u     // float [4 arrays][8 chunks][NB*NHW] (k_dots partials)
// total = 756736 + 4*8*32768*4 = 4,951,040 B

// ---------------------------------------------------------------------------
// Wave-64 sum via DPP (VALU pipe only, no LDS). Result valid in lane 63.
template<int CTRL>
__device__ __forceinline__ float dpp_add(float x) {
    int y = __builtin_amdgcn_update_dpp(0, __float_as_int(x), CTRL, 0xf, 0xf, false);
    return x + __int_as_float(y);
}
__device__ __forceinline__ float wave64_sum(float x) {
    x = dpp_add<0x111>(x);   // row_shr:1
    x = dpp_add<0x112>(x);   // row_shr:2
    x = dpp_add<0x114>(x);   // row_shr:4
    x = dpp_add<0x118>(x);   // row_shr:8  -> lane15 of each row16 has row sum
    x = dpp_add<0x142>(x);   // row_bcast:15 -> lane31/63 have half sums
    x = dpp_add<0x143>(x);   // row_bcast:31 -> lane63 has total
    return x;
}

// ---------------------------------------------------------------------------
// Kernel 1: nearest-resize labels + per-batch class counts (64 blocks).
// Per-block LDS hist -> one float atomicAdd per (block,class); integer-valued
// f32 adds are exact and order-independent. counts zeroed by memset upstream.
__global__ __launch_bounds__(256) void k_labels(const int* __restrict__ target,
                                                int* __restrict__ labels,
                                                float* __restrict__ counts) {
    __shared__ int hist[NCLS];
    const int blk = blockIdx.x;          // 0..63
    const int b    = blk >> 3;
    const int part = blk & (LBLK - 1);   // 512-pixel slice
    const int t = threadIdx.x;
    if (t < NCLS) hist[t] = 0;
    __syncthreads();
    const int* tb = target + (size_t)b * 512 * 512;
    #pragma unroll
    for (int i = 0; i < 2; ++i) {
        int n = part * 512 + t + i * 256;
        int y = n >> 6, x = n & 63;
        int l = tb[(y * 8) * 512 + x * 8];   // in_idx = floor(out_idx*512/64)
        labels[b * NHW + n] = l;
        if (l >= 0 && l < NCLS) atomicAdd(&hist[l], 1);
    }
    __syncthreads();
    if (t < NCLS && hist[t] > 0)
        atomicAdd(&counts[b * NCLS + t], (float)hist[t]);
}

// ---------------------------------------------------------------------------
// Kernel 2: per-class channel sums, LDS column-private float2 accumulator,
// FULL UP-FRONT LOAD + sched_barrier pin (this round's single variable).
//
// ALGORITHM HISTORY (load-bearing):
//   r0-r4/r6 mask-accumulate O(19)/elem: ~57 us VALU floor.
//   r5 LDS atomics: 174 us (colliding ds_add serializes per-lane). Poison.
//   r7 column scatter b32: 51 us.  r8 packed float2 b64: 48.6 us.
//   r10 depth-1 source prefetch: DEFEATED BY COMPILER (VGPR stayed 52 ->
//     prefetch regs never allocated; -2 us was the label batch only).
//   Standing symptom: all pipes <20% busy, 66 MB HBM fetch at 1.5 TB/s
//     (~50% L3 miss: 2x128MB feature passes/iter thrash the 256MB L3).
//     Demand-latency theory: VGPR=52 -> ~3 loads in flight/wave.
// THIS VERSION: all 12 float4 + 4 int4 loads issued up front into named
//   registers, pinned by __builtin_amdgcn_sched_barrier(0) (loads cannot
//   sink). Deliberate TLP->MLP trade: VGPR ~100-120 -> 8 waves/CU (LDS
//   would allow 16), but in-flight bytes/CU ~96 KB >> the ~9 KB/CU
//   Little's-law need for full HBM BW at ~900cy miss latency.
// EXECUTION CHECK: VGPR must jump to ~100+. If still ~52 -> compiler won
//   again; next step inline-asm loads. If VGPR ~110 but flat ~45 us ->
//   hard pattern wall; k_sums done, pivot to k_dots.
//
// Block = (b, channel c); 4096 blocks x 256 thr; LDS 38912 B.
__global__ __launch_bounds__(256) void k_sums(const float* __restrict__ fS,
                                              const float* __restrict__ fT,
                                              const int* __restrict__ labels,
                                              float* __restrict__ sumsS,
                                              float* __restrict__ sumsT) {
    __shared__ float2 acc[NCLS * 256];   // 38912 B
    const int t   = threadIdx.x;
    const int blk = blockIdx.x;          // 0..4095
    const int b   = blk >> 9;            // 512 channels per batch
    const int c   = blk & (NC - 1);

    const int4*   lab4 = (const int4*)(labels + b * NHW);
    const float4* pS   = (const float4*)(fS + ((size_t)(b * NC) + c) * NHW);
    const float4* pT   = (const float4*)(fT + ((size_t)(b * NC) + c) * NHW);

    // Issue ALL loads before any LDS work; sched_barrier(0) forbids the
    // scheduler from sinking them below (r10 lesson: without this, hipcc
    // folds the pipeline away — VGPR_Count is the execution proof).
    int4 lab[4]; float4 vS[4]; float4 vT[4];
    #pragma unroll
    for (int j = 0; j < 4; ++j) {
        lab[j] = lab4[t + (j << 8)];
        vS[j]  = pS[t + (j << 8)];
        vT[j]  = pT[t + (j << 8)];
    }
    __builtin_amdgcn_sched_barrier(0);

    {   // zero LDS, vectorized: 19*256*8B / 16B = 2432 float4
        float4* av = (float4*)acc;
        const float4 z = make_float4(0.f, 0.f, 0.f, 0.f);
        for (int i = t; i < NCLS * 128; i += 256) av[i] = z;
    }
    __syncthreads();

    float2* a0 = acc + t;                // element k at a0[k<<8]

    #pragma unroll
    for (int j = 0; j < 4; ++j) {        // fully unrolled: static reg indices
        const int4   l = lab[j];
        const float4 s = vS[j];
        const float4 u = vT[j];
        if ((unsigned)l.x < NCLS) { float2 v = a0[l.x << 8]; v.x += s.x; v.y += u.x; a0[l.x << 8] = v; }
        if ((unsigned)l.y < NCLS) { float2 v = a0[l.y << 8]; v.x += s.y; v.y += u.y; a0[l.y << 8] = v; }
        if ((unsigned)l.z < NCLS) { float2 v = a0[l.z << 8]; v.x += s.z; v.y += u.z; a0[l.z << 8] = v; }
        if ((unsigned)l.w < NCLS) { float2 v = a0[l.w << 8]; v.x += s.w; v.y += u.w; a0[l.w << 8] = v; }
    }
    __syncthreads();

    // Reduce 19 float2-rows of 256; rows round-robin over the 4 waves.
    const int w = t >> 6, lane = t & 63;
    for (int r = w; r < NCLS; r += 4) {
        const float2* row = acc + r * 256;
        const float2 p0 = row[lane], p1 = row[lane + 64];
        const float2 p2 = row[lane + 128], p3 = row[lane + 192];
        float sx = (p0.x + p1.x) + (p2.x + p3.x);
        float sy = (p0.y + p1.y) + (p2.y + p3.y);
        sx = wave64_sum(sx);
        sy = wave64_sum(sy);
        if (lane == 63) {
            sumsS[((size_t)(b * NCLS + r)) * NC + c] = sx;
            sumsT[((size_t)(b * NCLS + r)) * NC + c] = sy;
        }
    }
}

// ---------------------------------------------------------------------------
// Kernel 3: means = sums/(count+eps) in place + per-(b,k) center norms.
// One wave per (b,k); sums layout [b][k][c] -> coalesced.
__global__ __launch_bounds__(64) void k_means(float* __restrict__ sumsS,
                                              float* __restrict__ sumsT,
                                              const float* __restrict__ counts,
                                              float* __restrict__ normS,
                                              float* __restrict__ normT) {
    const int bk = blockIdx.x;
    const int t = threadIdx.x;
    const float inv = 1.f / (counts[bk] + EPSM);
    float* rS = sumsS + (size_t)bk * NC;
    float* rT = sumsT + (size_t)bk * NC;
    float aS = 0.f, aT = 0.f;
    #pragma unroll
    for (int i = 0; i < NC / 64; ++i) {
        float mS = rS[t + i * 64] * inv; rS[t + i * 64] = mS; aS += mS * mS;
        float mT = rT[t + i * 64] * inv; rT[t + i * 64] = mT; aT += mT * mT;
    }
    aS = wave64_sum(aS);
    aT = wave64_sum(aT);
    if (t == 63) { normS[bk] = sqrtf(aS); normT[bk] = sqrtf(aT); }
}

// ---------------------------------------------------------------------------
// Kernel 4: per-pixel dot(f, mean[lab]) and ||f||^2, atomic-free.
// Grid: 8 b x 16 pixel-tiles x 8 c-chunks = 1024 blocks.
// Means tile in LDS as [class][65] -> gather bank = (l+ci)%32, conflict-free.
#define CCH 64
__global__ __launch_bounds__(256) void k_dots(const float* __restrict__ fS,
                                              const float* __restrict__ fT,
                                              const float* __restrict__ meansS,
                                              const float* __restrict__ meansT,
                                              const int* __restrict__ labels,
                                              float* __restrict__ part) {
    __shared__ float mS[NCLS * 65];
    __shared__ float mT[NCLS * 65];
    const int blk = blockIdx.x;
    const int chunk = blk & 7;
    const int tile  = (blk >> 3) & 15;
    const int b     = blk >> 7;
    const int t = threadIdx.x;
    const int c0 = chunk * CCH;
    const int n = tile * 256 + t;

    for (int i = t; i < NCLS * CCH; i += 256) {
        const int k = i >> 6, j = i & 63;
        mS[k * 65 + j] = meansS[((size_t)(b * NCLS + k)) * NC + c0 + j];
        mT[k * 65 + j] = meansT[((size_t)(b * NCLS + k)) * NC + c0 + j];
    }
    __syncthreads();

    const int l = labels[b * NHW + n];
    const int lc = (l >= 0 && l < NCLS) ? l : 0;
    const float* pS = fS + ((size_t)(b * NC + c0)) * NHW + n;
    const float* pT = fT + ((size_t)(b * NC + c0)) * NHW + n;
    float dS = 0.f, nS = 0.f, dT = 0.f, nT = 0.f;
    #pragma unroll 8
    for (int ci = 0; ci < CCH; ++ci) {
        const float vS = pS[(size_t)ci * NHW];
        const float vT = pT[(size_t)ci * NHW];
        const float ms = mS[lc * 65 + ci];
        const float mt = mT[lc * 65 + ci];
        dS += vS * ms; nS += vS * vS;
        dT += vT * mt; nT += vT * vT;
    }
    const int p = b * NHW + n;
    part[((size_t)(0 * 8 + chunk)) * (NB * NHW) + p] = dS;
    part[((size_t)(1 * 8 + chunk)) * (NB * NHW) + p] = nS;
    part[((size_t)(2 * 8 + chunk)) * (NB * NHW) + p] = dT;
    part[((size_t)(3 * 8 + chunk)) * (NB * NHW) + p] = nT;
}

// ---------------------------------------------------------------------------
// Kernel 5: combine partials, cosines, MSE reduce.
__global__ __launch_bounds__(256) void k_final(const float* __restrict__ part,
                                               const int* __restrict__ labels,
                                               const float* __restrict__ normS,
                                               const float* __restrict__ normT,
                                               float* __restrict__ out) {
    __shared__ float red[4];
    const int p = blockIdx.x * 256 + threadIdx.x;
    const int b = p >> 12;
    float dS = 0.f, nS = 0.f, dT = 0.f, nT = 0.f;
    #pragma unroll
    for (int ch = 0; ch < 8; ++ch) {
        dS += part[((size_t)(0 * 8 + ch)) * (NB * NHW) + p];
        nS += part[((size_t)(1 * 8 + ch)) * (NB * NHW) + p];
        dT += part[((size_t)(2 * 8 + ch)) * (NB * NHW) + p];
        nT += part[((size_t)(3 * 8 + ch)) * (NB * NHW) + p];
    }
    const int l = labels[p];
    float val = 0.f;
    if (l >= 0 && l < NCLS) {
        float cS = dS / (fmaxf(sqrtf(nS), EPSC) * fmaxf(normS[b * NCLS + l], EPSC));
        float cT = dT / (fmaxf(sqrtf(nT), EPSC) * fmaxf(normT[b * NCLS + l], EPSC));
        float d = cS - cT;
        val = d * d;
    }
    val = wave64_sum(val);
    if ((threadIdx.x & 63) == 63) red[threadIdx.x >> 6] = val;
    __syncthreads();
    if (threadIdx.x == 0)
        atomicAdd(out, (red[0] + red[1] + red[2] + red[3]) * (1.f / (NB * NHW)));
}

// ---------------------------------------------------------------------------
extern "C" void kernel_launch(void* const* d_in, const int* in_sizes, int n_in,
                              void* d_out, int out_size, void* d_ws, size_t ws_size,
                              hipStream_t stream) {
    (void)in_sizes; (void)n_in; (void)out_size; (void)ws_size;
    const float* fS     = (const float*)d_in[0];
    const float* fT     = (const float*)d_in[1];
    const int*   target = (const int*)d_in[2];

    char* ws = (char*)d_ws;
    int*   labels = (int*)  (ws + OFF_LABELS);
    float* counts = (float*)(ws + OFF_COUNTS);
    float* sumsS  = (float*)(ws + OFF_SUMS_S);   // means after k_means (in place)
    float* sumsT  = (float*)(ws + OFF_SUMS_T);
    float* normS  = (float*)(ws + OFF_NORM_S);
    float* normT  = (float*)(ws + OFF_NORM_T);
    float* part   = (float*)(ws + OFF_PART);

    hipMemsetAsync(d_out, 0, sizeof(float), stream);
    hipMemsetAsync(counts, 0, NB * NCLS * sizeof(float), stream);

    k_labels<<<NB * LBLK, 256, 0, stream>>>(target, labels, counts);
    k_sums  <<<NB * NC, 256, 0, stream>>>(fS, fT, labels, sumsS, sumsT);
    k_means <<<NB * NCLS, 64, 0, stream>>>(sumsS, sumsT, counts, normS, normT);
    k_dots  <<<NB * 16 * 8, 256, 0, stream>>>(fS, fT, sumsS, sumsT, labels, part);
    k_final <<<NB * NHW / 256, 256, 0, stream>>>(part, labels, normS, normT,
                                                 (float*)d_out);
}